// Round 14
// baseline (6295.572 us; speedup 1.0000x reference)
//
#include <hip/hip_runtime.h>

#define TST 1024
#define NB  256
#define NT  320            // 4 own waves (16x16) + 1 poller wave (64 halo cells)

typedef float v4f __attribute__((ext_vector_type(4)));

#define AG __HIP_MEMORY_SCOPE_AGENT
__device__ __forceinline__ float agload (const float* p){ return __hip_atomic_load (p, __ATOMIC_RELAXED, AG); }
__device__ __forceinline__ int   agloadi(const int* p)  { return __hip_atomic_load (p, __ATOMIC_RELAXED, AG); }
__device__ __forceinline__ void  agstoref(float* p,float v){      __hip_atomic_store(p, v, __ATOMIC_RELAXED, AG); }
__device__ __forceinline__ void  agstorei(int* p,int v) {         __hip_atomic_store(p, v, __ATOMIC_RELAXED, AG); }

// Device-scope (sc1) 16B accesses, coherent at Infinity Cache. Stamp rides in
// .w -> each slot self-validates. Load+waitcnt in ONE asm block (R5 fault:
// split issue/wait lets regalloc retire the dest quad before the write lands).
__device__ __forceinline__ v4f ld16_dev(const v4f* p) {
    v4f r;
    asm volatile("global_load_dwordx4 %0, %1, off sc1\n\ts_waitcnt vmcnt(0)"
                 : "=v"(r) : "v"(p) : "memory");
    return r;
}
__device__ __forceinline__ void st16_dev(v4f* p, v4f v) {
    asm volatile("global_store_dwordx4 %0, %1, off sc1" :: "v"(p), "v"(v) : "memory");
}

__global__ void __launch_bounds__(NT)
mm_solver(const float* __restrict__ signal,
          const float* __restrict__ B_ext,
          const float* __restrict__ Msat,
          const float* __restrict__ src_mask,
          const float* __restrict__ probe_mask,
          float* __restrict__ out,
          float* __restrict__ ws)
{
    const int b  = (int)blockIdx.x;
    const int bx = b & 15, by = b >> 4;
    const int t  = (int)threadIdx.x;
    const int wv = t >> 6;                         // 0..3 own, 4 poller
    const bool isOwn = (t < 256);
    const bool lane0 = ((t & 63) == 0);

    // ws: pub v4f[2][65536] (2MB) | priv float[NB][TST] (1MB) | doneA int[NB]
    v4f*   pub   = (v4f*)ws;
    float* priv  = ws + 2 * 65536 * 4;
    int*   doneA = (int*)(priv + NB * TST);
    const int pubStride = 65536;

    // 18x18 eval field, double-buffered; ring (outer 1-ring, no corners) is
    // written ONLY by the poller wave, interior ONLY by own threads.
    __shared__ v4f  E0[324];
    __shared__ v4f  E1[324];
    __shared__ float sigS[TST];
    __shared__ int  wctr[6];                       // sentinels + own waves 0..3
    __shared__ int  w4c;                           // poller phase counter
    __shared__ int  hasP;
    __shared__ int  pfl[NB];
    __shared__ float redS[5];
    __shared__ float pmsS;

    // constants (identical fp expressions to the bitwise-validated R1-R13 kernels)
    const float invd   = (float)(1.0 / (double)((float)(50e-9 * 50e-9)));
    const float h      = (float)(1.7595e11 * 5e-12);
    const float hh     = (float)(0.5 * (1.7595e11 * 5e-12));
    const float h6     = (float)((1.7595e11 * 5e-12) / 6.0);
    const float alpha  = 0.01f;
    const float inv1a2 = (float)(1.0 / (1.0 + 0.01 * 0.01));

    // ---- role setup ----
    int  eidx = 0, offU = 0, offD = 0, offR = 0, offL = 0, slotP = 0;
    bool pubT = false;
    int  hidx = 0, slotL = 0; bool hvalid = false;
    float bxv = 0, byv = 0, bzv = 0, ms = 0, sxv = 0, syv = 0, szv = 0, pm = 0;
    float ce = 0, cdem = 0;
    float mx = 0.0f, my = 0.0f, mz = 1.0f;     // m0 = z-hat (relax is bitwise
                                               // identity: zero torque; R1-R13
                                               // measured absmax 0.0)
    if (isOwn) {
        const int r = t >> 4, c = t & 15;
        const int grow = by * 16 + r, gcol = bx * 16 + c;   // always in-grid
        const int idxg = grow * 256 + gcol;
        bxv = B_ext[idxg]; byv = B_ext[65536 + idxg]; bzv = B_ext[131072 + idxg];
        ms  = Msat[idxg];
        sxv = src_mask[idxg]; syv = src_mask[65536 + idxg]; szv = src_mask[131072 + idxg];
        pm  = probe_mask[idxg];
        ce   = 7.3e-12f / ms;
        cdem = -(float)(4.0e-7 * 3.14159265358979323846) * ms;
        eidx = (r + 1) * 18 + (c + 1);
        // physical Neumann = clamp-to-self (bitwise = R4-R13 semantics)
        offU = (grow < 255) ?  18 : 0;
        offD = (grow > 0)   ? -18 : 0;
        offR = (gcol < 255) ?   1 : 0;
        offL = (gcol > 0)   ?  -1 : 0;
        pubT = (r == 0) | (r == 15) | (c == 0) | (c == 15);
        slotP = idxg;
    } else {
        const int k = t - 256, side = k >> 4, j = k & 15;
        int hr, hc;
        if      (side == 0) { hr = -1; hc = j;  }
        else if (side == 1) { hr = 16; hc = j;  }
        else if (side == 2) { hr = j;  hc = -1; }
        else                { hr = j;  hc = 16; }
        const int grow = by * 16 + hr, gcol = bx * 16 + hc;
        hvalid = (grow >= 0 && grow < 256 && gcol >= 0 && gcol < 256);
        hidx   = (hr + 1) * 18 + (hc + 1);
        slotL  = hvalid ? grow * 256 + gcol : 0;
    }

    // ---- init: expose m0 (phase 0) ----
    if (isOwn) {
        E0[eidx] = (v4f){0.0f, 0.0f, 1.0f, 0.0f};
        if (pubT) st16_dev(pub + slotP, (v4f){0.0f, 0.0f, 1.0f, __int_as_float(0)});
    }
    for (int k = t; k < TST; k += NT) sigS[k] = signal[k];
    if (t < 6)  wctr[t] = (t == 0 || t == 5) ? 0x7fffffff : 0;   // own ctr=0: E0
    if (t == 6) { volatile int* vw = &w4c; *vw = -1; }           // writes committed
    if (t == 7) hasP = 0;                                        // at __syncthreads
    __syncthreads();
    const bool pcell = isOwn && (pm != 0.0f);
    if (pcell) atomicOr(&hasP, 1);
    const bool waveP = (__ballot(pcell) != 0ull);                // wave-uniform
    __syncthreads();
    const int hasPr = hasP;
    if (hasPr) for (int k = t; k < TST; k += NT) agstoref(&priv[b * TST + k], 0.0f);
    __syncthreads();   // TRUE barrier: zero-stores drained before step-0 atomics

#define STAGE(EP, exv, eyv, ezv, btxv, btyv, btzv) do { \
    const v4f u = (EP)[eidx + offU]; \
    const v4f d = (EP)[eidx + offD]; \
    const v4f r = (EP)[eidx + offR]; \
    const v4f l = (EP)[eidx + offL]; \
    float lx = ((u.x + d.x - 2.0f * exv) + (r.x + l.x - 2.0f * exv)) * invd; \
    float ly = ((u.y + d.y - 2.0f * eyv) + (r.y + l.y - 2.0f * eyv)) * invd; \
    float lz = ((u.z + d.z - 2.0f * ezv) + (r.z + l.z - 2.0f * ezv)) * invd; \
    float Bx = btxv + ce * lx; \
    float By = btyv + ce * ly; \
    float Bz = btzv + ce * lz + cdem * ezv; \
    float cx = eyv * Bz - ezv * By; \
    float cy = ezv * Bx - exv * Bz; \
    float cz = exv * By - eyv * Bx; \
    float dx = eyv * cz - ezv * cy; \
    float dy = ezv * cx - exv * cz; \
    float dz = exv * cy - eyv * cx; \
    kx = -(cx + alpha * dx) * inv1a2; \
    ky = -(cy + alpha * dy) * inv1a2; \
    kz = -(cz + alpha * dz) * inv1a2; \
} while (0)

    if (isOwn) {
        // ---- own waves: phase-pipelined RK4, phases g = 4i+1..4i+4 ----
        // Phase g reads E[(g-1)&1] (needs nbr-wave ctrs >= g-1 AND poller
        // ring w4c >= g-1), writes E[g&1] (overwrites phase g-2, whose readers
        // finished at ctr >= g-1 — same spin covers it), boundary publishes
        // e^g with stamp g to parity g&1 (vmcnt-drained: slot reused at g+2,
        // and the drain orders same-address stores), then bumps its counter.
        volatile int* cl  = (volatile int*)&wctr[wv];
        volatile int* cr  = (volatile int*)&wctr[wv + 2];
        volatile int* cme = (volatile int*)&wctr[wv + 1];
        volatile int* vw4 = (volatile int*)&w4c;
        float ex, ey, ez, ax, ay, az, kx, ky, kz, btx, bty, btz;

#define SPIN_OWN(G) do { \
    while (*cl  < (G)) {} \
    while (*cr  < (G)) {} \
    while (*vw4 < (G)) {} \
    asm volatile("" ::: "memory"); \
} while (0)
#define PUB_CTR(G) do { \
    asm volatile("s_waitcnt lgkmcnt(0)" ::: "memory"); \
    if (lane0) *cme = (G); \
    asm volatile("" ::: "memory"); \
} while (0)
#define PUBE(G, PX, PY, PZ) do { \
    if (pubT) { \
        asm volatile("s_waitcnt vmcnt(0)" ::: "memory"); \
        st16_dev(pub + ((G) & 1) * pubStride + slotP, \
                 (v4f){PX, PY, PZ, __int_as_float(G)}); \
    } \
} while (0)

        for (int i = 0; i < TST; ++i) {
            const float s = sigS[i];
            const int g0 = i << 2;
            btx = bxv + s * sxv;  bty = byv + s * syv;  btz = bzv + s * szv;

            SPIN_OWN(g0);                       // m_i field (incl. ring) ready
            ex = mx; ey = my; ez = mz;
            STAGE(E0, ex, ey, ez, btx, bty, btz);             // k1
            ax = kx; ay = ky; az = kz;
            ex = mx + hh * kx; ey = my + hh * ky; ez = mz + hh * kz;
            E1[eidx] = (v4f){ex, ey, ez, 0.0f};
            PUBE(g0 + 1, ex, ey, ez);
            PUB_CTR(g0 + 1);

            SPIN_OWN(g0 + 1);
            STAGE(E1, ex, ey, ez, btx, bty, btz);             // k2
            ax += 2.0f * kx; ay += 2.0f * ky; az += 2.0f * kz;
            ex = mx + hh * kx; ey = my + hh * ky; ez = mz + hh * kz;
            E0[eidx] = (v4f){ex, ey, ez, 0.0f};
            PUBE(g0 + 2, ex, ey, ez);
            PUB_CTR(g0 + 2);

            SPIN_OWN(g0 + 2);
            STAGE(E0, ex, ey, ez, btx, bty, btz);             // k3
            ax += 2.0f * kx; ay += 2.0f * ky; az += 2.0f * kz;
            ex = mx + h * kx; ey = my + h * ky; ez = mz + h * kz;
            E1[eidx] = (v4f){ex, ey, ez, 0.0f};
            PUBE(g0 + 3, ex, ey, ez);
            PUB_CTR(g0 + 3);

            SPIN_OWN(g0 + 3);
            STAGE(E1, ex, ey, ez, btx, bty, btz);             // k4
            ax += kx; ay += ky; az += kz;
            mx += h6 * ax; my += h6 * ay; mz += h6 * az;
            E0[eidx] = (v4f){mx, my, mz, 0.0f};               // = e0 of step i+1
            PUBE(g0 + 4, mx, my, mz);
            PUB_CTR(g0 + 4);

            // probe: (mx - m0x) = mx exactly; per-wave reduce -> one atomic
            if (waveP) {
                float c = pcell ? mx * ms * pm : 0.0f;
                #pragma unroll
                for (int off = 32; off > 0; off >>= 1) c += __shfl_down(c, off, 64);
                if (lane0) atomicAdd(&priv[b * TST + i], c);
            }
        }
    } else {
        // ---- poller wave: per phase g, fetch the 64 halo slots into the ring.
        // Buffer safety: ring of E[g&1] was last written at phase g-2; its
        // readers are the phase-(g-1) computes -> spin own ctrs >= g-1 first.
        // Cross-block stamps: neighbor overwrites its parity-g slot with g+2
        // only after observing OUR g+1 publishes, which require our waves'
        // phase g+1, which requires THIS ring write (w4c >= g) -> our poll
        // bound first. Monotone counters -> deadlock-free.
        volatile int* vc  = (volatile int*)wctr;
        volatile int* vw4 = (volatile int*)&w4c;
        for (int g = 0; g <= 4095; ++g) {
            const int gm = g - 1;
            for (;;) {
                if (vc[1] >= gm && vc[2] >= gm && vc[3] >= gm && vc[4] >= gm) break;
            }
            asm volatile("" ::: "memory");
            v4f hv = (v4f){0.0f, 0.0f, 0.0f, 0.0f};
            const v4f* p = pub + (g & 1) * pubStride + slotL;
            for (;;) {
                v4f tmp = (v4f){0.0f, 0.0f, 0.0f, 0.0f};
                if (hvalid) { tmp = ld16_dev(p); hv = tmp; }
                const bool need = hvalid && (__float_as_int(tmp.w) < g);
                if (__ballot(need) == 0ull) break;
            }
            if (hvalid) { if (g & 1) E1[hidx] = hv; else E0[hidx] = hv; }
            asm volatile("s_waitcnt lgkmcnt(0)" ::: "memory");
            if (t == 256) *vw4 = g;
            asm volatile("" ::: "memory");
        }
    }

    // ---- finalize ----
    __syncthreads();   // TRUE barrier: drains vmcnt -> publishes/atomics done
    if (t == 0) agstorei(&doneA[b], 0x5D0000 | hasPr);

    if (b == 0) {
        if (t < NB) {
            int v;
            for (;;) { v = agloadi(&doneA[t]); if ((v & ~1) == 0x5D0000) break;
                       __builtin_amdgcn_s_sleep(8); }
            pfl[t] = v & 1;
        }
        __syncthreads();
        float ps = 0.0f;
        for (int k = t; k < 65536; k += NT) ps += probe_mask[k];
        #pragma unroll
        for (int off = 32; off > 0; off >>= 1) ps += __shfl_down(ps, off, 64);
        if (lane0) redS[wv] = ps;
        __syncthreads();
        if (t == 0) { float q = 0.0f; for (int w = 0; w < 5; ++w) q += redS[w]; pmsS = q; }
        __syncthreads();
        const float pms = pmsS;
        for (int o = t; o < TST; o += NT) {
            float sm = 0.0f;
            for (int j = 0; j < NB; ++j) if (pfl[j]) sm += agload(&priv[j * TST + o]);
            out[o] = sm / pms;
        }
    }
}

extern "C" void kernel_launch(void* const* d_in, const int* in_sizes, int n_in,
                              void* d_out, int out_size, void* d_ws, size_t ws_size,
                              hipStream_t stream)
{
    const float* signal = (const float*)d_in[0];
    const float* B_ext  = (const float*)d_in[1];
    const float* Msat   = (const float*)d_in[2];
    const float* src    = (const float*)d_in[3];
    const float* probe  = (const float*)d_in[4];
    float* out = (float*)d_out;
    float* ws  = (float*)d_ws;

    void* args[] = { &signal, &B_ext, &Msat, &src, &probe, &out, &ws };
    (void)in_sizes; (void)n_in; (void)out_size; (void)ws_size;

    // 256 blocks x 320 threads: 4 own waves (16x16 cells, zero redundant halo
    // compute) + 1 poller wave fetching the 64-cell 1-ring every RK4 stage.
    // All sync: LDS phase counters intra-block, stamped IF$ slots inter-block.
    hipLaunchCooperativeKernel(reinterpret_cast<void*>(mm_solver),
                               dim3(NB), dim3(NT), args, 0, stream);
}